// Round 18
// baseline (195.883 us; speedup 1.0000x reference)
//
#include <hip/hip_runtime.h>
#include <hip/hip_bf16.h>
#include <stdint.h>

#define SEQLEN   1024
#define DMODEL   2048
#define DINNER   4096
#define NHEADS   64
#define HEADDIM  64
#define DSTATE   64
#define CONVDIM  4224
#define DINPROJ  8384
#define RMS_EPS  1e-5f
#define CPAD     68
#define LP       72     // intra LDS row pitch in bf16 (144B)

typedef __attribute__((ext_vector_type(8))) __bf16 bf16x8;
typedef __attribute__((ext_vector_type(8))) unsigned short us8;
typedef __attribute__((ext_vector_type(4))) float f32x4;

__device__ __forceinline__ ushort f2bf(float f) {
    uint32_t u = __float_as_uint(f);
    u += 0x7FFFu + ((u >> 16) & 1u);   // round-to-nearest-even
    return (ushort)(u >> 16);
}

__device__ __forceinline__ float bf2f(ushort u) {
    return __uint_as_float((uint32_t)u << 16);
}

__device__ __forceinline__ float silu(float a) { return a / (1.f + __expf(-a)); }

__device__ __forceinline__ void gload_lds16(const void* g, void* l) {
    __builtin_amdgcn_global_load_lds(
        (const __attribute__((address_space(1))) void*)g,
        (__attribute__((address_space(3))) void*)l, 16, 0, 0);
}

// ---------------------------------------------------------------- cvt f32->bf16 (3 segments) + ssbuf zero
__global__ __launch_bounds__(256) void cvt3_kernel(
    const float* __restrict__ a, ushort* __restrict__ oa, int na4,
    const float* __restrict__ b, ushort* __restrict__ ob, int nb4,
    const float* __restrict__ c, ushort* __restrict__ oc, int nc4,
    float* __restrict__ ssbuf)
{
    int i = blockIdx.x * 256 + threadIdx.x;
    if (blockIdx.x == 0) {                      // zero ssbuf[1024] (replaces memset)
        float4 z = {0.f, 0.f, 0.f, 0.f};
        ((float4*)ssbuf)[threadIdx.x] = z;
    }
    const float* src; ushort* dst;
    if (i < na4) { src = a; dst = oa; }
    else if (i < na4 + nb4) { i -= na4; src = b; dst = ob; }
    else { i -= na4 + nb4; if (i >= nc4) return; src = c; dst = oc; }
    float4 v = ((const float4*)src)[i];
    ushort4 o;
    o.x = f2bf(v.x); o.y = f2bf(v.y); o.z = f2bf(v.z); o.w = f2bf(v.w);
    ((ushort4*)dst)[i] = o;
}

// ---------------------------------------------------------------- 4-wave BM=64 BN=128 BK=32 2-phase bf16 GEMM
// Same proven 2-phase schedule/swizzle as R10/R11; tile halved in M so the
// grid supplies ~4 co-resident blocks/CU (528->1056 blocks) -- cross-block
// overlap is the one lever with consistent measured wins. 24KB LDS,
// acc[2][4]=32 VGPR (no spill risk under (256,4)).
__global__ __launch_bounds__(256, 4) void gemm4_bf16_nt(
    const __bf16* __restrict__ A, const __bf16* __restrict__ B,
    float* __restrict__ C, int M, int N, int K,
    int ntx, int nty, int nk, int ksteps, int swz)
{
    __shared__ __align__(16) __bf16 As[2][64 * 32];
    __shared__ __align__(16) __bf16 Bs[2][128 * 32];
    const int tid  = threadIdx.x;
    const int lane = tid & 63;
    const int wave = tid >> 6;
    const int wr = wave >> 1, wc = wave & 1;     // wr: M half (32 rows), wc: N half (64 cols)
    int id = blockIdx.x;
    if (swz) { int q = (ntx * nty * nk) >> 3; id = (id & 7) * q + (id >> 3); }
    const int kz  = id / (ntx * nty);
    const int rem = id % (ntx * nty);
    const int tx = rem / nty, ty = rem % nty;    // column-major: ids share B-strip
    const int row0 = ty * 64, col0 = tx * 128;
    const int lr = lane & 15, lq = lane >> 4;
    const int rA = lane >> 2, jl = lane & 3;
    const int k0 = kz * ksteps * 32;

    // A: 1 gload/wave (16 rows); B: 2 gloads/wave (32 rows). Pre-swizzled src.
    const __bf16* srcA;
    const __bf16* srcB[2];
    int dstA, dstB[2];
    {
        int r0 = wave * 16;
        int r  = r0 + rA;
        int jg = jl ^ ((rA >> 1) & 3);
        srcA = A + (size_t)(row0 + r) * K + k0 + jg * 8;
        dstA = r0 * 32;
    }
    #pragma unroll
    for (int e = 0; e < 2; ++e) {
        int r0 = (wave * 2 + e) * 16;
        int r  = r0 + rA;
        int jg = jl ^ ((rA >> 1) & 3);
        int gb = col0 + r; if (gb > N - 1) gb = N - 1;
        srcB[e] = B + (size_t)gb * K + k0 + jg * 8;
        dstB[e] = r0 * 32;
    }

    f32x4 acc[2][4] = {};
    const int nt = ksteps;

#define STAGE(BUF)                                                            \
    {                                                                         \
        gload_lds16(srcA, &As[BUF][dstA]);                                    \
        srcA += 32;                                                           \
        _Pragma("unroll")                                                     \
        for (int e = 0; e < 2; ++e) {                                         \
            gload_lds16(srcB[e], &Bs[BUF][dstB[e]]);                          \
            srcB[e] += 32;                                                    \
        }                                                                     \
    }

#define COMPUTE(BUF)                                                          \
    {                                                                         \
        bf16x8 af[2], bfr[4];                                                 \
        const int sl = (lq ^ ((lr >> 1) & 3)) * 8;                            \
        _Pragma("unroll")                                                     \
        for (int m = 0; m < 2; ++m) {                                         \
            int r = wr * 32 + m * 16 + lr;                                    \
            af[m] = *(const bf16x8*)(&As[BUF][r * 32 + sl]);                  \
        }                                                                     \
        _Pragma("unroll")                                                     \
        for (int n = 0; n < 4; ++n) {                                         \
            int r = wc * 64 + n * 16 + lr;                                    \
            bfr[n] = *(const bf16x8*)(&Bs[BUF][r * 32 + sl]);                 \
        }                                                                     \
        __builtin_amdgcn_s_setprio(1);                                        \
        _Pragma("unroll")                                                     \
        for (int m = 0; m < 2; ++m)                                           \
            _Pragma("unroll")                                                 \
            for (int n = 0; n < 4; ++n)                                       \
                acc[m][n] = __builtin_amdgcn_mfma_f32_16x16x32_bf16(af[m], bfr[n], acc[m][n], 0, 0, 0); \
        __builtin_amdgcn_s_setprio(0);                                        \
    }

    STAGE(0);
    asm volatile("s_waitcnt vmcnt(0)" ::: "memory");
    __builtin_amdgcn_s_barrier();
    asm volatile("" ::: "memory");

    for (int t = 0; t < nt; t += 2) {
        STAGE(1);
        COMPUTE(0);
        asm volatile("s_waitcnt vmcnt(0)" ::: "memory");
        __builtin_amdgcn_s_barrier();
        asm volatile("" ::: "memory");
        if (t + 2 < nt) { STAGE(0); }
        COMPUTE(1);
        asm volatile("s_waitcnt vmcnt(0)" ::: "memory");
        __builtin_amdgcn_s_barrier();
        asm volatile("" ::: "memory");
    }
#undef STAGE
#undef COMPUTE

    float* Co = C + (size_t)kz * M * N;
    #pragma unroll
    for (int m = 0; m < 2; ++m)
        #pragma unroll
        for (int n = 0; n < 4; ++n) {
            int col = col0 + wc * 64 + n * 16 + lr;
            if (col < N) {
                #pragma unroll
                for (int j = 0; j < 4; ++j) {
                    int row = row0 + wr * 32 + m * 16 + lq * 4 + j;
                    Co[(size_t)row * N + col] = acc[m][n][j];
                }
            }
        }
}

// ---------------------------------------------------------------- split-K reduce (4) + row RMS scale
__global__ __launch_bounds__(256) void reduce4_scale_kernel(
    const float* __restrict__ p, const float* __restrict__ ssbuf,
    float* __restrict__ out, int n4)
{
    int i = blockIdx.x * 256 + threadIdx.x;
    if (i < n4) {
        int t = i >> 9;
        float sc = rsqrtf(ssbuf[t] * (1.f / DINNER) + RMS_EPS);
        float4 a = ((const float4*)p)[i];
        float4 b = ((const float4*)p)[i + n4];
        float4 c = ((const float4*)p)[i + 2 * (size_t)n4];
        float4 d = ((const float4*)p)[i + 3 * (size_t)n4];
        float4 o = {(a.x + b.x + c.x + d.x) * sc, (a.y + b.y + c.y + d.y) * sc,
                    (a.z + b.z + c.z + d.z) * sc, (a.w + b.w + c.w + d.w) * sc};
        ((float4*)out)[i] = o;
    }
}

// ---------------------------------------------------------------- chunked scan A: conv + intra (MFMA)
__global__ __launch_bounds__(256, 4) void chunk_intra_kernel(
    const float* __restrict__ zx, const float* __restrict__ conv_w,
    const float* __restrict__ conv_b, const float* __restrict__ dt_bias,
    const float* __restrict__ A_log,
    float* __restrict__ x_scan, float* __restrict__ Cb,
    float* __restrict__ yintra, float* __restrict__ Tc, float* __restrict__ Ssum)
{
    const int head  = blockIdx.x >> 4;
    const int chunk = blockIdx.x & 15;
    const int t0 = chunk * 64;
    const int tid = threadIdx.x;
    const int lane = tid & 63, wv = tid >> 6;
    const int lr = lane & 15, lq = lane >> 4;

    __shared__ __align__(16) ushort XT [64 * LP];  // [p][s]
    __shared__ __align__(16) ushort Crm[64 * LP];  // [i][n] -> reused as G[i][s]
    __shared__ __align__(16) ushort Brm[64 * LP];  // [s][n]
    __shared__ __align__(16) ushort BnT[64 * LP];  // [n][s]
    __shared__ float Sc[64], dts[64], ws[64];

    {
        const int p = lane;
        const int c = head * 64 + p;
        const float w0 = conv_w[c*4+0], w1 = conv_w[c*4+1];
        const float w2 = conv_w[c*4+2], w3 = conv_w[c*4+3];
        const float bia = conv_b[c];
        const int gt0 = t0 + wv * 16;
        const float* zc = zx + DINNER + c;
        float xm3 = (gt0 >= 3) ? zc[(size_t)(gt0-3)*DINPROJ] : 0.f;
        float xm2 = (gt0 >= 2) ? zc[(size_t)(gt0-2)*DINPROJ] : 0.f;
        float xm1 = (gt0 >= 1) ? zc[(size_t)(gt0-1)*DINPROJ] : 0.f;
        uint32_t pk[8];
        #pragma unroll
        for (int e = 0; e < 16; ++e) {
            float xt = zc[(size_t)(gt0+e)*DINPROJ];
            float s  = silu(bia + xm3*w0 + xm2*w1 + xm1*w2 + xt*w3);
            x_scan[(size_t)(gt0+e)*DINNER + c] = s;
            ushort b = f2bf(s);
            if (e & 1) pk[e>>1] |= (uint32_t)b << 16; else pk[e>>1] = (uint32_t)b;
            xm3 = xm2; xm2 = xm1; xm1 = xt;
        }
        int4 lo = { (int)pk[0], (int)pk[1], (int)pk[2], (int)pk[3] };
        int4 hi = { (int)pk[4], (int)pk[5], (int)pk[6], (int)pk[7] };
        *(int4*)&XT[p * LP + wv*16]     = lo;
        *(int4*)&XT[p * LP + wv*16 + 8] = hi;
    }

    #pragma unroll
    for (int k = 0; k < 4; ++k) {
        int n0 = wv * 16 + k * 4;
        int gt = t0 + lane;
        {   // B
            float4 w0 = *(const float4*)&conv_w[(4096 + n0 + 0) * 4];
            float4 w1 = *(const float4*)&conv_w[(4096 + n0 + 1) * 4];
            float4 w2 = *(const float4*)&conv_w[(4096 + n0 + 2) * 4];
            float4 w3 = *(const float4*)&conv_w[(4096 + n0 + 3) * 4];
            float4 bv = *(const float4*)&conv_b[4096 + n0];
            float4 r0 = {0,0,0,0}, r1 = {0,0,0,0}, r2 = {0,0,0,0}, r3;
            const float* base = zx + (size_t)gt * DINPROJ + 8192 + n0;
            if (gt >= 3) r0 = *(const float4*)(base - 3 * DINPROJ);
            if (gt >= 2) r1 = *(const float4*)(base - 2 * DINPROJ);
            if (gt >= 1) r2 = *(const float4*)(base - 1 * DINPROJ);
            r3 = *(const float4*)base;
            ushort b0 = f2bf(silu(bv.x + r0.x*w0.x + r1.x*w0.y + r2.x*w0.z + r3.x*w0.w));
            ushort b1 = f2bf(silu(bv.y + r0.y*w1.x + r1.y*w1.y + r2.y*w1.z + r3.y*w1.w));
            ushort b2 = f2bf(silu(bv.z + r0.z*w2.x + r1.z*w2.y + r2.z*w2.z + r3.z*w2.w));
            ushort b3 = f2bf(silu(bv.w + r0.w*w3.x + r1.w*w3.y + r2.w*w3.z + r3.w*w3.w));
            uint2 pk = { (uint32_t)b0 | ((uint32_t)b1 << 16),
                         (uint32_t)b2 | ((uint32_t)b3 << 16) };
            *(uint2*)&Brm[lane * LP + n0] = pk;
            BnT[(n0+0)*LP + lane] = b0; BnT[(n0+1)*LP + lane] = b1;
            BnT[(n0+2)*LP + lane] = b2; BnT[(n0+3)*LP + lane] = b3;
        }
        {   // C
            float4 w0 = *(const float4*)&conv_w[(4160 + n0 + 0) * 4];
            float4 w1 = *(const float4*)&conv_w[(4160 + n0 + 1) * 4];
            float4 w2 = *(const float4*)&conv_w[(4160 + n0 + 2) * 4];
            float4 w3 = *(const float4*)&conv_w[(4160 + n0 + 3) * 4];
            float4 bv = *(const float4*)&conv_b[4160 + n0];
            float4 r0 = {0,0,0,0}, r1 = {0,0,0,0}, r2 = {0,0,0,0}, r3;
            const float* base = zx + (size_t)gt * DINPROJ + 8256 + n0;
            if (gt >= 3) r0 = *(const float4*)(base - 3 * DINPROJ);
            if (gt >= 2) r1 = *(const float4*)(base - 2 * DINPROJ);
            if (gt >= 1) r2 = *(const float4*)(base - 1 * DINPROJ);
            r3 = *(const float4*)base;
            float4 cv;
            cv.x = silu(bv.x + r0.x*w0.x + r1.x*w0.y + r2.x*w0.z + r3.x*w0.w);
            cv.y = silu(bv.y + r0.y*w1.x + r1.y*w1.y + r2.y*w1.z + r3.y*w1.w);
            cv.z = silu(bv.z + r0.z*w2.x + r1.z*w2.y + r2.z*w2.z + r3.z*w2.w);
            cv.w = silu(bv.w + r0.w*w3.x + r1.w*w3.y + r2.w*w3.z + r3.w*w3.w);
            uint2 pk = { (uint32_t)f2bf(cv.x) | ((uint32_t)f2bf(cv.y) << 16),
                         (uint32_t)f2bf(cv.z) | ((uint32_t)f2bf(cv.w) << 16) };
            *(uint2*)&Crm[lane * LP + n0] = pk;
            if (head == 0) *(float4*)&Cb[(size_t)gt * 64 + n0] = cv;
        }
    }

    if (wv == 1) {
        float raw = zx[(size_t)(t0 + lane) * DINPROJ + 8320 + head] + dt_bias[head];
        float dt  = (raw > 20.f) ? raw : log1pf(__expf(raw));
        dts[lane] = dt;
        float v = dt * (-__expf(A_log[head]));
        #pragma unroll
        for (int off = 1; off < 64; off <<= 1) {
            float u = __shfl_up(v, off, 64);
            if (lane >= off) v += u;
        }
        Sc[lane] = v;
        Ssum[(t0 + lane) * 64 + head] = v;
    }
    __syncthreads();
    if (tid < 64) ws[tid] = dts[tid] * __expf(Sc[63] - Sc[tid]);

    const int i0 = wv * 16;
    f32x4 gf[4] = {};
    #pragma unroll
    for (int kk = 0; kk < 2; ++kk) {
        bf16x8 a = __builtin_bit_cast(bf16x8,
            *(const us8*)&Crm[(i0 + lr) * LP + lq*8 + kk*32]);
        #pragma unroll
        for (int f = 0; f < 4; ++f) {
            bf16x8 b = __builtin_bit_cast(bf16x8,
                *(const us8*)&Brm[(f*16 + lr) * LP + lq*8 + kk*32]);
            gf[f] = __builtin_amdgcn_mfma_f32_16x16x32_bf16(a, b, gf[f], 0, 0, 0);
        }
    }
    {
        float Si[4];
        #pragma unroll
        for (int j = 0; j < 4; ++j) Si[j] = Sc[i0 + lq*4 + j];
        #pragma unroll
        for (int f = 0; f < 4; ++f) {
            int s = f*16 + lr;
            float dw = dts[s], Ss_ = Sc[s];
            #pragma unroll
            for (int j = 0; j < 4; ++j) {
                int i = i0 + lq*4 + j;
                float v = (s <= i) ? gf[f][j] * dw * __expf(Si[j] - Ss_) : 0.f;
                Crm[i * LP + s] = f2bf(v);
            }
        }
    }
    __syncthreads();

    const int p0 = i0;
    bf16x8 xa[2], xw[2];
    #pragma unroll
    for (int kk = 0; kk < 2; ++kk) {
        us8 raw = *(const us8*)&XT[(p0 + lr) * LP + lq*8 + kk*32];
        xa[kk] = __builtin_bit_cast(bf16x8, raw);
        us8 sw;
        #pragma unroll
        for (int e = 0; e < 8; ++e) {
            int s = lq*8 + kk*32 + e;
            sw[e] = f2bf(bf2f(raw[e]) * ws[s]);
        }
        xw[kk] = __builtin_bit_cast(bf16x8, sw);
    }
    f32x4 yf[4] = {};
    f32x4 tf[4] = {};
    #pragma unroll
    for (int kk = 0; kk < 2; ++kk) {
        #pragma unroll
        for (int f = 0; f < 4; ++f) {
            bf16x8 gb = __builtin_bit_cast(bf16x8,
                *(const us8*)&Crm[(f*16 + lr) * LP + lq*8 + kk*32]);
            yf[f] = __builtin_amdgcn_mfma_f32_16x16x32_bf16(xa[kk], gb, yf[f], 0, 0, 0);
            bf16x8 bb = __builtin_bit_cast(bf16x8,
                *(const us8*)&BnT[(f*16 + lr) * LP + lq*8 + kk*32]);
            tf[f] = __builtin_amdgcn_mfma_f32_16x16x32_bf16(xw[kk], bb, tf[f], 0, 0, 0);
        }
    }
    float* tcb = Tc + (size_t)(head * 16 + chunk) * 4096;
    #pragma unroll
    for (int f = 0; f < 4; ++f) {
        int col = f*16 + lr;
        int p   = p0 + lq*4;
        float4 yv = {yf[f][0], yf[f][1], yf[f][2], yf[f][3]};
        *(float4*)&yintra[(size_t)(t0 + col) * DINNER + head*64 + p] = yv;
        #pragma unroll
        for (int j = 0; j < 4; ++j)
            tcb[(p + j) * 64 + col] = tf[f][j];
    }
}

// ---------------------------------------------------------------- chunked scan B: serial carry
__global__ __launch_bounds__(256) void chunk_state_kernel(
    float* __restrict__ Tc, const float* __restrict__ Ssum)
{
    const int head = blockIdx.x;
    const int tid = threadIdx.x;
    float h[16] = {};
    float* base = Tc + (size_t)head * 16 * 4096 + tid * 16;
    for (int c = 0; c < 16; ++c) {
        float Q = __expf(Ssum[(c * 64 + 63) * 64 + head]);
        float4* p = (float4*)(base + (size_t)c * 4096);
        #pragma unroll
        for (int v = 0; v < 4; ++v) {
            float4 t = p[v];
            float4 hold = {h[v*4], h[v*4+1], h[v*4+2], h[v*4+3]};
            h[v*4+0] = h[v*4+0] * Q + t.x;
            h[v*4+1] = h[v*4+1] * Q + t.y;
            h[v*4+2] = h[v*4+2] * Q + t.z;
            h[v*4+3] = h[v*4+3] * Q + t.w;
            p[v] = hold;
        }
    }
}

// ---------------------------------------------------------------- inter-chunk + gate + norm-weight (fused)
__global__ __launch_bounds__(256) void inter_combine_kernel(
    const float* __restrict__ Hpre, const float* __restrict__ Cb,
    const float* __restrict__ Ssum, const float* __restrict__ yintra,
    const float* __restrict__ x_scan, const float* __restrict__ zx,
    const float* __restrict__ Dv, const float* __restrict__ norm_w,
    ushort* __restrict__ ybf, float* __restrict__ ssbuf)
{
    const int head  = blockIdx.x >> 4;
    const int chunk = blockIdx.x & 15;
    const int t0 = chunk * 64;
    const int tid = threadIdx.x;
    const int ty = tid >> 4, tx = tid & 15;
    const int lane = tid & 63, wv = tid >> 6;

    __shared__ __align__(16) float HsT[64][CPAD];
    __shared__ __align__(16) float CsT[64][CPAD];
    __shared__ float Se[64];

    const float* hb = Hpre + (size_t)(head * 16 + chunk) * 4096;
    #pragma unroll
    for (int k = 0; k < 4; ++k) {
        int n0 = wv * 16 + k * 4;
        float4 h = *(const float4*)&hb[lane * 64 + n0];
        float4 c = *(const float4*)&Cb[(t0 + lane) * 64 + n0];
        HsT[n0][lane] = h.x; HsT[n0+1][lane] = h.y; HsT[n0+2][lane] = h.z; HsT[n0+3][lane] = h.w;
        CsT[n0][lane] = c.x; CsT[n0+1][lane] = c.y; CsT[n0+2][lane] = c.z; CsT[n0+3][lane] = c.w;
    }
    if (tid < 64) Se[tid] = __expf(Ssum[(t0 + tid) * 64 + head]);
    __syncthreads();

    float acc[4][4] = {};
    for (int n = 0; n < 64; ++n) {
        float4 ci = *(const float4*)&CsT[n][ty * 4];
        float4 hp = *(const float4*)&HsT[n][tx * 4];
        acc[0][0] += ci.x*hp.x; acc[0][1] += ci.x*hp.y; acc[0][2] += ci.x*hp.z; acc[0][3] += ci.x*hp.w;
        acc[1][0] += ci.y*hp.x; acc[1][1] += ci.y*hp.y; acc[1][2] += ci.y*hp.z; acc[1][3] += ci.y*hp.w;
        acc[2][0] += ci.z*hp.x; acc[2][1] += ci.z*hp.y; acc[2][2] += ci.z*hp.z; acc[2][3] += ci.z*hp.w;
        acc[3][0] += ci.w*hp.x; acc[3][1] += ci.w*hp.y; acc[3][2] += ci.w*hp.z; acc[3][3] += ci.w*hp.w;
    }

    const float Dh = Dv[head];
    const int col = head * 64 + tx * 4;
    float4 nw = *(const float4*)&norm_w[col];
    float ssp[4];
    #pragma unroll
    for (int di = 0; di < 4; ++di) {
        int t = t0 + ty * 4 + di;
        float se = Se[ty * 4 + di];
        float4 yi = *(const float4*)&yintra[(size_t)t * DINNER + col];
        float4 xh = *(const float4*)&x_scan[(size_t)t * DINNER + col];
        float4 zv = *(const float4*)&zx[(size_t)t * DINPROJ + col];
        float4 y;
        y.x = (acc[di][0] * se + yi.x + Dh * xh.x) * silu(zv.x);
        y.y = (acc[di][1] * se + yi.y + Dh * xh.y) * silu(zv.y);
        y.z = (acc[di][2] * se + yi.z + Dh * xh.z) * silu(zv.z);
        y.w = (acc[di][3] * se + yi.w + Dh * xh.w) * silu(zv.w);
        ssp[di] = y.x*y.x + y.y*y.y + y.z*y.z + y.w*y.w;
        ushort4 o;
        o.x = f2bf(y.x * nw.x); o.y = f2bf(y.y * nw.y);
        o.z = f2bf(y.z * nw.z); o.w = f2bf(y.w * nw.w);
        *(ushort4*)&ybf[(size_t)t * DINNER + col] = o;
    }
    #pragma unroll
    for (int di = 0; di < 4; ++di) {
        float s = ssp[di];
        s += __shfl_xor(s, 1, 64);
        s += __shfl_xor(s, 2, 64);
        s += __shfl_xor(s, 4, 64);
        s += __shfl_xor(s, 8, 64);
        if (tx == 0) atomicAdd(&ssbuf[t0 + ty * 4 + di], s);
    }
}

// ---------------------------------------------------------------- launch
extern "C" void kernel_launch(void* const* d_in, const int* in_sizes, int n_in,
                              void* d_out, int out_size, void* d_ws, size_t ws_size,
                              hipStream_t stream)
{
    const float* x       = (const float*)d_in[0];
    const float* W_in    = (const float*)d_in[1];
    const float* conv_w  = (const float*)d_in[2];
    const float* conv_b  = (const float*)d_in[3];
    const float* dt_bias = (const float*)d_in[4];
    const float* A_log   = (const float*)d_in[5];
    const float* Dv      = (const float*)d_in[6];
    const float* norm_w  = (const float*)d_in[7];
    const float* W_out   = (const float*)d_in[8];
    float* out = (float*)d_out;

    char* ws = (char*)d_ws;
    const size_t OFF_WIN  = 0;                     // bf16 W_in / later yintra / gemm2 partials
    const size_t OFF_WOUT = 34340864;
    const size_t OFF_XBF  = OFF_WOUT + 16777216;
    const size_t OFF_ZX   = OFF_XBF + 4194304;
    const size_t OFF_XSC  = OFF_ZX + 34340864;
    const size_t OFF_CB   = OFF_XSC + 16777216;
    const size_t OFF_SSB  = OFF_CB + 262144;
    const size_t OFF_YBF  = OFF_SSB + 4096;
    const size_t OFF_TC   = OFF_YBF + 8388608;
    const size_t OFF_SS   = OFF_TC + 16777216;

    ushort* WinBf  = (ushort*)(ws + OFF_WIN);
    ushort* WoutBf = (ushort*)(ws + OFF_WOUT);
    ushort* xBf    = (ushort*)(ws + OFF_XBF);
    float*  zxb    = (float*)(ws + OFF_ZX);
    float*  xsc    = (float*)(ws + OFF_XSC);
    float*  Cb     = (float*)(ws + OFF_CB);
    float*  ssbuf  = (float*)(ws + OFF_SSB);
    ushort* ybf    = (ushort*)(ws + OFF_YBF);
    float*  Tc     = (float*)(ws + OFF_TC);
    float*  Ssum   = (float*)(ws + OFF_SS);
    float*  yintra = (float*)(ws + OFF_WIN);       // alias (WinBf dead after gemm1)
    float*  part   = (float*)(ws + OFF_WIN);       // alias (yintra dead after inter_combine)

    const int nW4 = DINPROJ * DMODEL / 4;
    const int nO4 = DMODEL * DINNER / 4;
    const int nX4 = SEQLEN * DMODEL / 4;
    const int nAll = nW4 + nO4 + nX4;
    cvt3_kernel<<<(nAll + 255) / 256, 256, 0, stream>>>(
        W_in, WinBf, nW4, W_out, WoutBf, nO4, x, xBf, nX4, ssbuf);

    // gemm1: [1024 x 8384] = x * W_in^T ; BM=64: 16x66 = 1056 blocks (~4/CU), nt=64
    gemm4_bf16_nt<<<1056, 256, 0, stream>>>(
        (const __bf16*)xBf, (const __bf16*)WinBf, zxb,
        SEQLEN, DINPROJ, DMODEL, 66, 16, 1, DMODEL / 32, 1);

    chunk_intra_kernel<<<1024, 256, 0, stream>>>(
        zxb, conv_w, conv_b, dt_bias, A_log, xsc, Cb, yintra, Tc, Ssum);

    chunk_state_kernel<<<64, 256, 0, stream>>>(Tc, Ssum);

    inter_combine_kernel<<<1024, 256, 0, stream>>>(
        Tc, Cb, Ssum, yintra, xsc, zxb, Dv, norm_w, ybf, ssbuf);

    // gemm2: [1024 x 2048] = y * W_out^T ; BM=64: 16x16 x split-K=4 = 1024 blocks (4/CU), nt=32
    gemm4_bf16_nt<<<1024, 256, 0, stream>>>(
        (const __bf16*)ybf, (const __bf16*)WoutBf, part,
        SEQLEN, DMODEL, DINNER, 16, 16, 4, DINNER / 32 / 4, 1);

    reduce4_scale_kernel<<<(SEQLEN * DMODEL / 4 + 255) / 256, 256, 0, stream>>>(
        part, ssbuf, out, SEQLEN * DMODEL / 4);
}

// Round 19
// 176.296 us; speedup vs baseline: 1.1111x; 1.1111x over previous
//
#include <hip/hip_runtime.h>
#include <hip/hip_bf16.h>
#include <stdint.h>

#define SEQLEN   1024
#define DMODEL   2048
#define DINNER   4096
#define NHEADS   64
#define HEADDIM  64
#define DSTATE   64
#define CONVDIM  4224
#define DINPROJ  8384
#define RMS_EPS  1e-5f
#define CPAD     68
#define LP       72     // intra LDS row pitch in bf16 (144B)

typedef __attribute__((ext_vector_type(8))) __bf16 bf16x8;
typedef __attribute__((ext_vector_type(8))) unsigned short us8;
typedef __attribute__((ext_vector_type(4))) float f32x4;

__device__ __forceinline__ ushort f2bf(float f) {
    uint32_t u = __float_as_uint(f);
    u += 0x7FFFu + ((u >> 16) & 1u);   // round-to-nearest-even
    return (ushort)(u >> 16);
}

__device__ __forceinline__ float bf2f(ushort u) {
    return __uint_as_float((uint32_t)u << 16);
}

__device__ __forceinline__ float silu(float a) { return a / (1.f + __expf(-a)); }

__device__ __forceinline__ void gload_lds16(const void* g, void* l) {
    __builtin_amdgcn_global_load_lds(
        (const __attribute__((address_space(1))) void*)g,
        (__attribute__((address_space(3))) void*)l, 16, 0, 0);
}

// ---------------------------------------------------------------- cvt f32->bf16 (W_in + x) + ssbuf zero
__global__ __launch_bounds__(256) void cvt2_kernel(
    const float* __restrict__ a, ushort* __restrict__ oa, int na4,
    const float* __restrict__ c, ushort* __restrict__ oc, int nc4,
    float* __restrict__ ssbuf)
{
    int i = blockIdx.x * 256 + threadIdx.x;
    if (blockIdx.x == 0) {                      // zero ssbuf[1024]
        float4 z = {0.f, 0.f, 0.f, 0.f};
        ((float4*)ssbuf)[threadIdx.x] = z;
    }
    const float* src; ushort* dst;
    if (i < na4) { src = a; dst = oa; }
    else { i -= na4; if (i >= nc4) return; src = c; dst = oc; }
    float4 v = ((const float4*)src)[i];
    ushort4 o;
    o.x = f2bf(v.x); o.y = f2bf(v.y); o.z = f2bf(v.z); o.w = f2bf(v.w);
    ((ushort4*)dst)[i] = o;
}

// ---------------------------------------------------------------- 4-wave BK=32 2-phase bf16 GEMM
// R17-proven config EXACTLY ((256,4), VGPR 64, 32KB LDS, 4/CU capable).
// Blocks with id >= ngemm piggyback a grid-stride f32->bf16 conversion
// (W_out for gemm2) -- rides in gemm1's idle memory BW (fetch only 15% peak).
__global__ __launch_bounds__(256, 4) void gemm4_bf16_nt(
    const __bf16* __restrict__ A, const __bf16* __restrict__ B,
    float* __restrict__ C, int M, int N, int K,
    int ntx, int nty, int nk, int ksteps, int swz, int ngemm,
    const float* __restrict__ cvt_src, ushort* __restrict__ cvt_dst, int cvt_n4)
{
    __shared__ __align__(16) __bf16 As[2][128 * 32];
    __shared__ __align__(16) __bf16 Bs[2][128 * 32];
    if (blockIdx.x >= ngemm) {                  // piggyback cvt block
        int nblk = gridDim.x - ngemm;
        for (int i = (blockIdx.x - ngemm) * 256 + threadIdx.x; i < cvt_n4;
             i += nblk * 256) {
            float4 v = ((const float4*)cvt_src)[i];
            ushort4 o;
            o.x = f2bf(v.x); o.y = f2bf(v.y); o.z = f2bf(v.z); o.w = f2bf(v.w);
            ((ushort4*)cvt_dst)[i] = o;
        }
        return;
    }
    const int tid  = threadIdx.x;
    const int lane = tid & 63;
    const int wave = tid >> 6;
    const int wr = wave >> 1, wc = wave & 1;
    int id = blockIdx.x;
    if (swz) { int q = (ntx * nty * nk) >> 3; id = (id & 7) * q + (id >> 3); }
    const int kz  = id / (ntx * nty);
    const int rem = id % (ntx * nty);
    const int tx = rem / nty, ty = rem % nty;   // column-major: ids share B-strip
    const int row0 = ty * 128, col0 = tx * 128;
    const int lr = lane & 15, lq = lane >> 4;
    const int rA = lane >> 2, jl = lane & 3;
    const int k0 = kz * ksteps * 32;

    const __bf16* srcA[2];
    const __bf16* srcB[2];
    int dstAB[2];
    #pragma unroll
    for (int e = 0; e < 2; ++e) {
        int r0 = (wave * 2 + e) * 16;
        int r  = r0 + rA;
        int jg = jl ^ ((rA >> 1) & 3);
        srcA[e] = A + (size_t)(row0 + r) * K + k0 + jg * 8;
        int gb = col0 + r; if (gb > N - 1) gb = N - 1;
        srcB[e] = B + (size_t)gb * K + k0 + jg * 8;
        dstAB[e] = r0 * 32;
    }

    f32x4 acc[4][4] = {};
    const int nt = ksteps;

#define STAGE(BUF)                                                            \
    _Pragma("unroll")                                                         \
    for (int e = 0; e < 2; ++e) {                                             \
        gload_lds16(srcA[e], &As[BUF][dstAB[e]]);                             \
        gload_lds16(srcB[e], &Bs[BUF][dstAB[e]]);                             \
        srcA[e] += 32; srcB[e] += 32;                                         \
    }

#define COMPUTE(BUF)                                                          \
    {                                                                         \
        bf16x8 af[4], bfr[4];                                                 \
        const int sl = (lq ^ ((lr >> 1) & 3)) * 8;                            \
        _Pragma("unroll")                                                     \
        for (int m = 0; m < 4; ++m) {                                         \
            int r = wr * 64 + m * 16 + lr;                                    \
            af[m] = *(const bf16x8*)(&As[BUF][r * 32 + sl]);                  \
        }                                                                     \
        _Pragma("unroll")                                                     \
        for (int n = 0; n < 4; ++n) {                                         \
            int r = wc * 64 + n * 16 + lr;                                    \
            bfr[n] = *(const bf16x8*)(&Bs[BUF][r * 32 + sl]);                 \
        }                                                                     \
        __builtin_amdgcn_s_setprio(1);                                        \
        _Pragma("unroll")                                                     \
        for (int m = 0; m < 4; ++m)                                           \
            _Pragma("unroll")                                                 \
            for (int n = 0; n < 4; ++n)                                       \
                acc[m][n] = __builtin_amdgcn_mfma_f32_16x16x32_bf16(af[m], bfr[n], acc[m][n], 0, 0, 0); \
        __builtin_amdgcn_s_setprio(0);                                        \
    }

    STAGE(0);
    asm volatile("s_waitcnt vmcnt(0)" ::: "memory");
    __builtin_amdgcn_s_barrier();
    asm volatile("" ::: "memory");

    for (int t = 0; t < nt; t += 2) {
        STAGE(1);
        COMPUTE(0);
        asm volatile("s_waitcnt vmcnt(0)" ::: "memory");
        __builtin_amdgcn_s_barrier();
        asm volatile("" ::: "memory");
        if (t + 2 < nt) { STAGE(0); }
        COMPUTE(1);
        asm volatile("s_waitcnt vmcnt(0)" ::: "memory");
        __builtin_amdgcn_s_barrier();
        asm volatile("" ::: "memory");
    }
#undef STAGE
#undef COMPUTE

    float* Co = C + (size_t)kz * M * N;
    #pragma unroll
    for (int m = 0; m < 4; ++m)
        #pragma unroll
        for (int n = 0; n < 4; ++n) {
            int col = col0 + wc * 64 + n * 16 + lr;
            if (col < N) {
                #pragma unroll
                for (int j = 0; j < 4; ++j) {
                    int row = row0 + wr * 64 + m * 16 + lq * 4 + j;
                    Co[(size_t)row * N + col] = acc[m][n][j];
                }
            }
        }
}

// ---------------------------------------------------------------- split-K reduce (4) + row RMS scale
__global__ __launch_bounds__(256) void reduce4_scale_kernel(
    const float* __restrict__ p, const float* __restrict__ ssbuf,
    float* __restrict__ out, int n4)
{
    int i = blockIdx.x * 256 + threadIdx.x;
    if (i < n4) {
        int t = i >> 9;
        float sc = rsqrtf(ssbuf[t] * (1.f / DINNER) + RMS_EPS);
        float4 a = ((const float4*)p)[i];
        float4 b = ((const float4*)p)[i + n4];
        float4 c = ((const float4*)p)[i + 2 * (size_t)n4];
        float4 d = ((const float4*)p)[i + 3 * (size_t)n4];
        float4 o = {(a.x + b.x + c.x + d.x) * sc, (a.y + b.y + c.y + d.y) * sc,
                    (a.z + b.z + c.z + d.z) * sc, (a.w + b.w + c.w + d.w) * sc};
        ((float4*)out)[i] = o;
    }
}

// ---------------------------------------------------------------- chunked scan A: conv + intra (MFMA)
__global__ __launch_bounds__(256, 4) void chunk_intra_kernel(
    const float* __restrict__ zx, const float* __restrict__ conv_w,
    const float* __restrict__ conv_b, const float* __restrict__ dt_bias,
    const float* __restrict__ A_log,
    float* __restrict__ x_scan, float* __restrict__ Cb,
    float* __restrict__ yintra, float* __restrict__ Tc, float* __restrict__ Ssum)
{
    const int head  = blockIdx.x >> 4;
    const int chunk = blockIdx.x & 15;
    const int t0 = chunk * 64;
    const int tid = threadIdx.x;
    const int lane = tid & 63, wv = tid >> 6;
    const int lr = lane & 15, lq = lane >> 4;

    __shared__ __align__(16) ushort XT [64 * LP];  // [p][s]
    __shared__ __align__(16) ushort Crm[64 * LP];  // [i][n] -> reused as G[i][s]
    __shared__ __align__(16) ushort Brm[64 * LP];  // [s][n]
    __shared__ __align__(16) ushort BnT[64 * LP];  // [n][s]
    __shared__ float Sc[64], dts[64], ws[64];

    {
        const int p = lane;
        const int c = head * 64 + p;
        const float w0 = conv_w[c*4+0], w1 = conv_w[c*4+1];
        const float w2 = conv_w[c*4+2], w3 = conv_w[c*4+3];
        const float bia = conv_b[c];
        const int gt0 = t0 + wv * 16;
        const float* zc = zx + DINNER + c;
        float xm3 = (gt0 >= 3) ? zc[(size_t)(gt0-3)*DINPROJ] : 0.f;
        float xm2 = (gt0 >= 2) ? zc[(size_t)(gt0-2)*DINPROJ] : 0.f;
        float xm1 = (gt0 >= 1) ? zc[(size_t)(gt0-1)*DINPROJ] : 0.f;
        uint32_t pk[8];
        #pragma unroll
        for (int e = 0; e < 16; ++e) {
            float xt = zc[(size_t)(gt0+e)*DINPROJ];
            float s  = silu(bia + xm3*w0 + xm2*w1 + xm1*w2 + xt*w3);
            x_scan[(size_t)(gt0+e)*DINNER + c] = s;
            ushort b = f2bf(s);
            if (e & 1) pk[e>>1] |= (uint32_t)b << 16; else pk[e>>1] = (uint32_t)b;
            xm3 = xm2; xm2 = xm1; xm1 = xt;
        }
        int4 lo = { (int)pk[0], (int)pk[1], (int)pk[2], (int)pk[3] };
        int4 hi = { (int)pk[4], (int)pk[5], (int)pk[6], (int)pk[7] };
        *(int4*)&XT[p * LP + wv*16]     = lo;
        *(int4*)&XT[p * LP + wv*16 + 8] = hi;
    }

    #pragma unroll
    for (int k = 0; k < 4; ++k) {
        int n0 = wv * 16 + k * 4;
        int gt = t0 + lane;
        {   // B
            float4 w0 = *(const float4*)&conv_w[(4096 + n0 + 0) * 4];
            float4 w1 = *(const float4*)&conv_w[(4096 + n0 + 1) * 4];
            float4 w2 = *(const float4*)&conv_w[(4096 + n0 + 2) * 4];
            float4 w3 = *(const float4*)&conv_w[(4096 + n0 + 3) * 4];
            float4 bv = *(const float4*)&conv_b[4096 + n0];
            float4 r0 = {0,0,0,0}, r1 = {0,0,0,0}, r2 = {0,0,0,0}, r3;
            const float* base = zx + (size_t)gt * DINPROJ + 8192 + n0;
            if (gt >= 3) r0 = *(const float4*)(base - 3 * DINPROJ);
            if (gt >= 2) r1 = *(const float4*)(base - 2 * DINPROJ);
            if (gt >= 1) r2 = *(const float4*)(base - 1 * DINPROJ);
            r3 = *(const float4*)base;
            ushort b0 = f2bf(silu(bv.x + r0.x*w0.x + r1.x*w0.y + r2.x*w0.z + r3.x*w0.w));
            ushort b1 = f2bf(silu(bv.y + r0.y*w1.x + r1.y*w1.y + r2.y*w1.z + r3.y*w1.w));
            ushort b2 = f2bf(silu(bv.z + r0.z*w2.x + r1.z*w2.y + r2.z*w2.z + r3.z*w2.w));
            ushort b3 = f2bf(silu(bv.w + r0.w*w3.x + r1.w*w3.y + r2.w*w3.z + r3.w*w3.w));
            uint2 pk = { (uint32_t)b0 | ((uint32_t)b1 << 16),
                         (uint32_t)b2 | ((uint32_t)b3 << 16) };
            *(uint2*)&Brm[lane * LP + n0] = pk;
            BnT[(n0+0)*LP + lane] = b0; BnT[(n0+1)*LP + lane] = b1;
            BnT[(n0+2)*LP + lane] = b2; BnT[(n0+3)*LP + lane] = b3;
        }
        {   // C
            float4 w0 = *(const float4*)&conv_w[(4160 + n0 + 0) * 4];
            float4 w1 = *(const float4*)&conv_w[(4160 + n0 + 1) * 4];
            float4 w2 = *(const float4*)&conv_w[(4160 + n0 + 2) * 4];
            float4 w3 = *(const float4*)&conv_w[(4160 + n0 + 3) * 4];
            float4 bv = *(const float4*)&conv_b[4160 + n0];
            float4 r0 = {0,0,0,0}, r1 = {0,0,0,0}, r2 = {0,0,0,0}, r3;
            const float* base = zx + (size_t)gt * DINPROJ + 8256 + n0;
            if (gt >= 3) r0 = *(const float4*)(base - 3 * DINPROJ);
            if (gt >= 2) r1 = *(const float4*)(base - 2 * DINPROJ);
            if (gt >= 1) r2 = *(const float4*)(base - 1 * DINPROJ);
            r3 = *(const float4*)base;
            float4 cv;
            cv.x = silu(bv.x + r0.x*w0.x + r1.x*w0.y + r2.x*w0.z + r3.x*w0.w);
            cv.y = silu(bv.y + r0.y*w1.x + r1.y*w1.y + r2.y*w1.z + r3.y*w1.w);
            cv.z = silu(bv.z + r0.z*w2.x + r1.z*w2.y + r2.z*w2.z + r3.z*w2.w);
            cv.w = silu(bv.w + r0.w*w3.x + r1.w*w3.y + r2.w*w3.z + r3.w*w3.w);
            uint2 pk = { (uint32_t)f2bf(cv.x) | ((uint32_t)f2bf(cv.y) << 16),
                         (uint32_t)f2bf(cv.z) | ((uint32_t)f2bf(cv.w) << 16) };
            *(uint2*)&Crm[lane * LP + n0] = pk;
            if (head == 0) *(float4*)&Cb[(size_t)gt * 64 + n0] = cv;
        }
    }

    if (wv == 1) {
        float raw = zx[(size_t)(t0 + lane) * DINPROJ + 8320 + head] + dt_bias[head];
        float dt  = (raw > 20.f) ? raw : log1pf(__expf(raw));
        dts[lane] = dt;
        float v = dt * (-__expf(A_log[head]));
        #pragma unroll
        for (int off = 1; off < 64; off <<= 1) {
            float u = __shfl_up(v, off, 64);
            if (lane >= off) v += u;
        }
        Sc[lane] = v;
        Ssum[(t0 + lane) * 64 + head] = v;
    }
    __syncthreads();
    if (tid < 64) ws[tid] = dts[tid] * __expf(Sc[63] - Sc[tid]);

    const int i0 = wv * 16;
    f32x4 gf[4] = {};
    #pragma unroll
    for (int kk = 0; kk < 2; ++kk) {
        bf16x8 a = __builtin_bit_cast(bf16x8,
            *(const us8*)&Crm[(i0 + lr) * LP + lq*8 + kk*32]);
        #pragma unroll
        for (int f = 0; f < 4; ++f) {
            bf16x8 b = __builtin_bit_cast(bf16x8,
                *(const us8*)&Brm[(f*16 + lr) * LP + lq*8 + kk*32]);
            gf[f] = __builtin_amdgcn_mfma_f32_16x16x32_bf16(a, b, gf[f], 0, 0, 0);
        }
    }
    {
        float Si[4];
        #pragma unroll
        for (int j = 0; j < 4; ++j) Si[j] = Sc[i0 + lq*4 + j];
        #pragma unroll
        for (int f = 0; f < 4; ++f) {
            int s = f*16 + lr;
            float dw = dts[s], Ss_ = Sc[s];
            #pragma unroll
            for (int j = 0; j < 4; ++j) {
                int i = i0 + lq*4 + j;
                float v = (s <= i) ? gf[f][j] * dw * __expf(Si[j] - Ss_) : 0.f;
                Crm[i * LP + s] = f2bf(v);
            }
        }
    }
    __syncthreads();

    const int p0 = i0;
    bf16x8 xa[2], xw[2];
    #pragma unroll
    for (int kk = 0; kk < 2; ++kk) {
        us8 raw = *(const us8*)&XT[(p0 + lr) * LP + lq*8 + kk*32];
        xa[kk] = __builtin_bit_cast(bf16x8, raw);
        us8 sw;
        #pragma unroll
        for (int e = 0; e < 8; ++e) {
            int s = lq*8 + kk*32 + e;
            sw[e] = f2bf(bf2f(raw[e]) * ws[s]);
        }
        xw[kk] = __builtin_bit_cast(bf16x8, sw);
    }
    f32x4 yf[4] = {};
    f32x4 tf[4] = {};
    #pragma unroll
    for (int kk = 0; kk < 2; ++kk) {
        #pragma unroll
        for (int f = 0; f < 4; ++f) {
            bf16x8 gb = __builtin_bit_cast(bf16x8,
                *(const us8*)&Crm[(f*16 + lr) * LP + lq*8 + kk*32]);
            yf[f] = __builtin_amdgcn_mfma_f32_16x16x32_bf16(xa[kk], gb, yf[f], 0, 0, 0);
            bf16x8 bb = __builtin_bit_cast(bf16x8,
                *(const us8*)&BnT[(f*16 + lr) * LP + lq*8 + kk*32]);
            tf[f] = __builtin_amdgcn_mfma_f32_16x16x32_bf16(xw[kk], bb, tf[f], 0, 0, 0);
        }
    }
    float* tcb = Tc + (size_t)(head * 16 + chunk) * 4096;
    #pragma unroll
    for (int f = 0; f < 4; ++f) {
        int col = f*16 + lr;
        int p   = p0 + lq*4;
        float4 yv = {yf[f][0], yf[f][1], yf[f][2], yf[f][3]};
        *(float4*)&yintra[(size_t)(t0 + col) * DINNER + head*64 + p] = yv;
        #pragma unroll
        for (int j = 0; j < 4; ++j)
            tcb[(p + j) * 64 + col] = tf[f][j];
    }
}

// ---------------------------------------------------------------- chunked scan B: serial carry
__global__ __launch_bounds__(256) void chunk_state_kernel(
    float* __restrict__ Tc, const float* __restrict__ Ssum)
{
    const int head = blockIdx.x;
    const int tid = threadIdx.x;
    float h[16] = {};
    float* base = Tc + (size_t)head * 16 * 4096 + tid * 16;
    for (int c = 0; c < 16; ++c) {
        float Q = __expf(Ssum[(c * 64 + 63) * 64 + head]);
        float4* p = (float4*)(base + (size_t)c * 4096);
        #pragma unroll
        for (int v = 0; v < 4; ++v) {
            float4 t = p[v];
            float4 hold = {h[v*4], h[v*4+1], h[v*4+2], h[v*4+3]};
            h[v*4+0] = h[v*4+0] * Q + t.x;
            h[v*4+1] = h[v*4+1] * Q + t.y;
            h[v*4+2] = h[v*4+2] * Q + t.z;
            h[v*4+3] = h[v*4+3] * Q + t.w;
            p[v] = hold;
        }
    }
}

// ---------------------------------------------------------------- inter-chunk + gate + norm-weight (fused)
__global__ __launch_bounds__(256) void inter_combine_kernel(
    const float* __restrict__ Hpre, const float* __restrict__ Cb,
    const float* __restrict__ Ssum, const float* __restrict__ yintra,
    const float* __restrict__ x_scan, const float* __restrict__ zx,
    const float* __restrict__ Dv, const float* __restrict__ norm_w,
    ushort* __restrict__ ybf, float* __restrict__ ssbuf)
{
    const int head  = blockIdx.x >> 4;
    const int chunk = blockIdx.x & 15;
    const int t0 = chunk * 64;
    const int tid = threadIdx.x;
    const int ty = tid >> 4, tx = tid & 15;
    const int lane = tid & 63, wv = tid >> 6;

    __shared__ __align__(16) float HsT[64][CPAD];
    __shared__ __align__(16) float CsT[64][CPAD];
    __shared__ float Se[64];

    const float* hb = Hpre + (size_t)(head * 16 + chunk) * 4096;
    #pragma unroll
    for (int k = 0; k < 4; ++k) {
        int n0 = wv * 16 + k * 4;
        float4 h = *(const float4*)&hb[lane * 64 + n0];
        float4 c = *(const float4*)&Cb[(t0 + lane) * 64 + n0];
        HsT[n0][lane] = h.x; HsT[n0+1][lane] = h.y; HsT[n0+2][lane] = h.z; HsT[n0+3][lane] = h.w;
        CsT[n0][lane] = c.x; CsT[n0+1][lane] = c.y; CsT[n0+2][lane] = c.z; CsT[n0+3][lane] = c.w;
    }
    if (tid < 64) Se[tid] = __expf(Ssum[(t0 + tid) * 64 + head]);
    __syncthreads();

    float acc[4][4] = {};
    for (int n = 0; n < 64; ++n) {
        float4 ci = *(const float4*)&CsT[n][ty * 4];
        float4 hp = *(const float4*)&HsT[n][tx * 4];
        acc[0][0] += ci.x*hp.x; acc[0][1] += ci.x*hp.y; acc[0][2] += ci.x*hp.z; acc[0][3] += ci.x*hp.w;
        acc[1][0] += ci.y*hp.x; acc[1][1] += ci.y*hp.y; acc[1][2] += ci.y*hp.z; acc[1][3] += ci.y*hp.w;
        acc[2][0] += ci.z*hp.x; acc[2][1] += ci.z*hp.y; acc[2][2] += ci.z*hp.z; acc[2][3] += ci.z*hp.w;
        acc[3][0] += ci.w*hp.x; acc[3][1] += ci.w*hp.y; acc[3][2] += ci.w*hp.z; acc[3][3] += ci.w*hp.w;
    }

    const float Dh = Dv[head];
    const int col = head * 64 + tx * 4;
    float4 nw = *(const float4*)&norm_w[col];
    float ssp[4];
    #pragma unroll
    for (int di = 0; di < 4; ++di) {
        int t = t0 + ty * 4 + di;
        float se = Se[ty * 4 + di];
        float4 yi = *(const float4*)&yintra[(size_t)t * DINNER + col];
        float4 xh = *(const float4*)&x_scan[(size_t)t * DINNER + col];
        float4 zv = *(const float4*)&zx[(size_t)t * DINPROJ + col];
        float4 y;
        y.x = (acc[di][0] * se + yi.x + Dh * xh.x) * silu(zv.x);
        y.y = (acc[di][1] * se + yi.y + Dh * xh.y) * silu(zv.y);
        y.z = (acc[di][2] * se + yi.z + Dh * xh.z) * silu(zv.z);
        y.w = (acc[di][3] * se + yi.w + Dh * xh.w) * silu(zv.w);
        ssp[di] = y.x*y.x + y.y*y.y + y.z*y.z + y.w*y.w;
        ushort4 o;
        o.x = f2bf(y.x * nw.x); o.y = f2bf(y.y * nw.y);
        o.z = f2bf(y.z * nw.z); o.w = f2bf(y.w * nw.w);
        *(ushort4*)&ybf[(size_t)t * DINNER + col] = o;
    }
    #pragma unroll
    for (int di = 0; di < 4; ++di) {
        float s = ssp[di];
        s += __shfl_xor(s, 1, 64);
        s += __shfl_xor(s, 2, 64);
        s += __shfl_xor(s, 4, 64);
        s += __shfl_xor(s, 8, 64);
        if (tx == 0) atomicAdd(&ssbuf[t0 + ty * 4 + di], s);
    }
}

// ---------------------------------------------------------------- launch
extern "C" void kernel_launch(void* const* d_in, const int* in_sizes, int n_in,
                              void* d_out, int out_size, void* d_ws, size_t ws_size,
                              hipStream_t stream)
{
    const float* x       = (const float*)d_in[0];
    const float* W_in    = (const float*)d_in[1];
    const float* conv_w  = (const float*)d_in[2];
    const float* conv_b  = (const float*)d_in[3];
    const float* dt_bias = (const float*)d_in[4];
    const float* A_log   = (const float*)d_in[5];
    const float* Dv      = (const float*)d_in[6];
    const float* norm_w  = (const float*)d_in[7];
    const float* W_out   = (const float*)d_in[8];
    float* out = (float*)d_out;

    char* ws = (char*)d_ws;
    const size_t OFF_WIN  = 0;                     // bf16 W_in / later yintra / gemm2 partials
    const size_t OFF_WOUT = 34340864;
    const size_t OFF_XBF  = OFF_WOUT + 16777216;
    const size_t OFF_ZX   = OFF_XBF + 4194304;
    const size_t OFF_XSC  = OFF_ZX + 34340864;
    const size_t OFF_CB   = OFF_XSC + 16777216;
    const size_t OFF_SSB  = OFF_CB + 262144;
    const size_t OFF_YBF  = OFF_SSB + 4096;
    const size_t OFF_TC   = OFF_YBF + 8388608;
    const size_t OFF_SS   = OFF_TC + 16777216;

    ushort* WinBf  = (ushort*)(ws + OFF_WIN);
    ushort* WoutBf = (ushort*)(ws + OFF_WOUT);
    ushort* xBf    = (ushort*)(ws + OFF_XBF);
    float*  zxb    = (float*)(ws + OFF_ZX);
    float*  xsc    = (float*)(ws + OFF_XSC);
    float*  Cb     = (float*)(ws + OFF_CB);
    float*  ssbuf  = (float*)(ws + OFF_SSB);
    ushort* ybf    = (ushort*)(ws + OFF_YBF);
    float*  Tc     = (float*)(ws + OFF_TC);
    float*  Ssum   = (float*)(ws + OFF_SS);
    float*  yintra = (float*)(ws + OFF_WIN);       // alias (WinBf dead after gemm1)
    float*  part   = (float*)(ws + OFF_WIN);       // alias (yintra dead after inter_combine)

    const int nW4 = DINPROJ * DMODEL / 4;
    const int nO4 = DMODEL * DINNER / 4;
    const int nX4 = SEQLEN * DMODEL / 4;
    cvt2_kernel<<<(nW4 + nX4 + 255) / 256, 256, 0, stream>>>(
        W_in, WinBf, nW4, x, xBf, nX4, ssbuf);

    // gemm1: 528 GEMM blocks + 160 piggyback blocks converting W_out f32->bf16
    gemm4_bf16_nt<<<528 + 160, 256, 0, stream>>>(
        (const __bf16*)xBf, (const __bf16*)WinBf, zxb,
        SEQLEN, DINPROJ, DMODEL, 66, 8, 1, DMODEL / 32, 1, 528,
        W_out, WoutBf, nO4);

    chunk_intra_kernel<<<1024, 256, 0, stream>>>(
        zxb, conv_w, conv_b, dt_bias, A_log, xsc, Cb, yintra, Tc, Ssum);

    chunk_state_kernel<<<64, 256, 0, stream>>>(Tc, Ssum);

    inter_combine_kernel<<<1024, 256, 0, stream>>>(
        Tc, Cb, Ssum, yintra, xsc, zxb, Dv, norm_w, ybf, ssbuf);

    // gemm2: [1024 x 2048] = y * W_out^T ; 16x8 x split-K=4 = 512 blocks, no piggyback
    gemm4_bf16_nt<<<512, 256, 0, stream>>>(
        (const __bf16*)ybf, (const __bf16*)WoutBf, part,
        SEQLEN, DMODEL, DINNER, 16, 8, 4, DINNER / 32 / 4, 1, 512,
        nullptr, nullptr, 0);

    reduce4_scale_kernel<<<(SEQLEN * DMODEL / 4 + 255) / 256, 256, 0, stream>>>(
        part, ssbuf, out, SEQLEN * DMODEL / 4);
}